// Round 6
// baseline (103.042 us; speedup 1.0000x reference)
//
#include <hip/hip_runtime.h>
#include <float.h>
#include <math.h>

// Problem constants (from reference setup_inputs)
#define B_ 4
#define N_ 4096
#define K_ 2048
#define TPB 256

// R13 = R11 structure (grid 1024 = 4 blocks/CU, dbuf tiles, folded coverage;
// R12's manual pipelining reverted) + two instruction-count reductions:
//   1. v_pk_fma_f32 packed fp32 (inline asm, op_sel broadcasts): distance
//      FMAs halved. Tile layout -> paired-AoS {x0,x1,y0,y1,z0,z1,w0,w1} so
//      candidate pairs load as aligned ds_read_b64 v2f with zero shuffle.
//   2. select8 (R7-validated) 16-cand windows: 4.875 sort-ops/cand vs 5.875.
//   role-3: 2 rows/thread packed + 1 cov row (cand-packed), 512 blocks
//   chamfer: 8 rows/thread as 4 packed row-pairs, 256 blocks/direction
#define R3_NB 512
#define CD_NB 256
#define GRID (R3_NB + 2 * CD_NB)  // 1024

// ws partial-sum layout (floats); every slot written every call -> no zeroing
#define WS_REP 0      // 512
#define WS_SMO 512    // 512
#define WS_CD1 1024   // 256
#define WS_CD2 1280   // 256
#define WS_COV 1536   // 512 (one per role-3 block)

// paired-AoS tiles (floats): pair-block = 8 floats {x0,x1,y0,y1,z0,z1,w0,w1},
// 4 v2f slots XOR-swizzled by ((pair>>2)&3) to spread write banks; reads are
// wave-uniform per group -> banks 4g + const, conflict-free.
// role-3: 16 groups x (32 pairs x 8 + 4 pad) = 16 x 260 = 4160 f/buffer
// cd:     32 groups x (16 pairs x 8 + 4 pad) = 32 x 132 = 4224 f/buffer
#define R3_GSTR2 130   // v2f stride per group
#define R3_BUF2 2080   // v2f per buffer
#define CD_GSTR2 66
#define CD_BUF2 2112
// role-3 epilogue areas (overlaid on buffers after the last tile barrier):
// merge lists 32 rows x 144 = [0..4608), aa [4608..4640), cov [4640..4912)
#define AA_OFF 4608
#define COV_OFF 4640
#define SMEM_F 8448    // floats = 33792 B -> 4 blocks/CU

typedef float v2f __attribute__((ext_vector_type(2)));

// v_pk_fma_f32 d = a*b + c. a = coefficient pair (natural lo/hi). Suffix:
// which half of b (and c for the *_bc* w-init forms) is broadcast to BOTH
// result halves via op_sel/op_sel_hi. Default convention: op_sel[k] picks the
// source half for the LOW result, op_sel_hi[k] for the HIGH result.
__device__ inline v2f pk_fma_n(v2f a, v2f b, v2f c) {
  v2f d;
  asm("v_pk_fma_f32 %0, %1, %2, %3 op_sel:[0,0,0] op_sel_hi:[1,1,1]"
      : "=v"(d) : "v"(a), "v"(b), "v"(c));
  return d;
}
__device__ inline v2f pk_fma_blo(v2f a, v2f b, v2f c) {
  v2f d;
  asm("v_pk_fma_f32 %0, %1, %2, %3 op_sel:[0,0,0] op_sel_hi:[1,0,1]"
      : "=v"(d) : "v"(a), "v"(b), "v"(c));
  return d;
}
__device__ inline v2f pk_fma_bhi(v2f a, v2f b, v2f c) {
  v2f d;
  asm("v_pk_fma_f32 %0, %1, %2, %3 op_sel:[0,1,0] op_sel_hi:[1,1,1]"
      : "=v"(d) : "v"(a), "v"(b), "v"(c));
  return d;
}
__device__ inline v2f pk_fma_bclo(v2f a, v2f b, v2f c) {
  v2f d;
  asm("v_pk_fma_f32 %0, %1, %2, %3 op_sel:[0,0,0] op_sel_hi:[1,0,0]"
      : "=v"(d) : "v"(a), "v"(b), "v"(c));
  return d;
}
__device__ inline v2f pk_fma_bchi(v2f a, v2f b, v2f c) {
  v2f d;
  asm("v_pk_fma_f32 %0, %1, %2, %3 op_sel:[0,1,1] op_sel_hi:[1,1,1]"
      : "=v"(d) : "v"(a), "v"(b), "v"(c));
  return d;
}

__device__ inline float wave_sum(float v) {
#pragma unroll
  for (int off = 32; off > 0; off >>= 1) v += __shfl_down(v, off, 64);
  return v;
}

__device__ inline void ce_asc(float& a, float& b) {
  float lo = fminf(a, b), hi = fmaxf(a, b);
  a = lo; b = hi;
}
__device__ inline void ce_desc(float& a, float& b) {
  float lo = fminf(a, b), hi = fmaxf(a, b);
  a = hi; b = lo;
}

// Batcher odd-even mergesort of 8, DESCENDING: 19 CEs (validated R6)
__device__ inline void bsort8_desc(float (&v)[8]) {
#define CE(i, j) ce_desc(v[i], v[j])
  CE(0,1); CE(2,3); CE(4,5); CE(6,7);
  CE(0,2); CE(1,3); CE(4,6); CE(5,7);
  CE(1,2); CE(5,6);
  CE(0,4); CE(1,5); CE(2,6); CE(3,7);
  CE(2,4); CE(3,5);
  CE(1,2); CE(3,4); CE(5,6);
#undef CE
}

__device__ inline void bitonic_merge8_asc(float (&v)[8]) {
#pragma unroll
  for (int j = 4; j > 0; j >>= 1) {
#pragma unroll
    for (int i = 0; i < 8; ++i) {
      int ixj = i ^ j;
      if (ixj > i) ce_asc(v[i], v[ixj]);
    }
  }
}
__device__ inline void bitonic_merge8_desc(float (&v)[8]) {
#pragma unroll
  for (int j = 4; j > 0; j >>= 1) {
#pragma unroll
    for (int i = 0; i < 8; ++i) {
      int ixj = i ^ j;
      if (ixj > i) ce_desc(v[i], v[ixj]);
    }
  }
}
__device__ inline void bitonic_merge16_asc(float (&v)[16]) {
#pragma unroll
  for (int j = 8; j > 0; j >>= 1) {
#pragma unroll
    for (int i = 0; i < 16; ++i) {
      int ixj = i ^ j;
      if (ixj > i) ce_asc(v[i], v[ixj]);
    }
  }
}

// Running t8 asc; 16 new candidates in s0,s1 (clobbered). Keep 8 smallest.
// (R7-validated): sort both desc; w[i]=min(s0[i],s1[7-i]) -> bitonic with 8
// smallest; sort w desc; t8=min(t8 asc, w desc) -> bitonic; restore asc.
__device__ inline void select8(float (&t8)[8], float (&s0)[8], float (&s1)[8]) {
  bsort8_desc(s0);
  bsort8_desc(s1);
  float w[8];
#pragma unroll
  for (int i = 0; i < 8; ++i) w[i] = fminf(s0[i], s1[7 - i]);
  bitonic_merge8_desc(w);
#pragma unroll
  for (int i = 0; i < 8; ++i) t8[i] = fminf(t8[i], w[i]);
  bitonic_merge8_asc(t8);
}

// L1: two ascending 8-lists at A[0..7] and A[9..16] -> ascending 16 in place
__device__ inline void fullmerge8_inplace(float* A) {
  float m[16];
#pragma unroll
  for (int i = 0; i < 8; ++i) m[i] = A[i];
#pragma unroll
  for (int i = 0; i < 8; ++i) m[8 + i] = A[9 + 7 - i];
  bitonic_merge16_asc(m);
#pragma unroll
  for (int i = 0; i < 16; ++i) A[i] = m[i];
}

// merge two ascending-16 lists -> 16 smallest ascending, stored to A
__device__ inline void keep16_lds(float* A, const float* Bl) {
  float m[16];
#pragma unroll
  for (int i = 0; i < 16; ++i) m[i] = fminf(A[i], Bl[15 - i]);
  bitonic_merge16_asc(m);
#pragma unroll
  for (int i = 0; i < 16; ++i) A[i] = m[i];
}

// Distances via s' = |c|^2 - 2 a.c (tile stores coords + |c|^2); |a|^2 added
// back after selection (monotone shift). Packed fma = same rounding as scalar
// fma -> numerics identical to R11 (absmax 3.7e-9). Role-3 top-8/thread
// exactness argument unchanged since R7.
__global__ __launch_bounds__(TPB, 3) void fused_loss(const float* __restrict__ pred,
                                                     const float* __restrict__ gt,
                                                     const float* __restrict__ partial,
                                                     float* __restrict__ ws) {
  __shared__ __align__(16) float smem_f[SMEM_F];
  v2f* tile2 = reinterpret_cast<v2f*>(smem_f);

  const int blk = blockIdx.x;
  const int t = threadIdx.x;

  // stage pair P (cands 2P,2P+1) from 3 held v2f {x0,y0}{z0,x1}{y1,z1}
#define PAIR_WRITE(dst2, P, GSH, GMSK, GSTR2, A, Bv, Cv)                       \
    {                                                                          \
      const int pi_ = (P) & (GMSK);                                            \
      const int sv_ = (pi_ >> 2) & 3;                                          \
      const int b2_ = ((P) >> (GSH)) * (GSTR2) + pi_ * 4;                      \
      const float w0_ = fmaf(A.x, A.x, fmaf(A.y, A.y, Bv.x * Bv.x));           \
      const float w1_ = fmaf(Bv.y, Bv.y, fmaf(Cv.x, Cv.x, Cv.y * Cv.y));       \
      v2f xw_ = {A.x, Bv.y}; v2f yw_ = {A.y, Cv.x};                            \
      v2f zw_ = {Bv.x, Cv.y}; v2f ww_ = {w0_, w1_};                            \
      dst2[b2_ + (0 ^ sv_)] = xw_; dst2[b2_ + (1 ^ sv_)] = yw_;                \
      dst2[b2_ + (2 ^ sv_)] = zw_; dst2[b2_ + (3 ^ sv_)] = ww_;                \
    }

  if (blk < R3_NB) {
    // ======= role 3: pred self top-16 (2 rows packed) + folded coverage =======
    const int r = t & 15;        // row slot
    const int g = t >> 4;        // group (16 groups x 64 cands = 32 pairs)
    const int gb2 = g * R3_GSTR2;
    const int rid = blk;
    const int b = rid >> 7;              // 128 blocks/batch
    const int row0 = (rid & 127) * 32;
    const int prow0 = (rid & 127) * 16;
    const size_t cbase = (size_t)b * N_ * 3;
    const v2f* gsrc = reinterpret_cast<const v2f*>(pred + cbase);

    // row coefficient pairs: rows (row0+r, row0+16+r)
    v2f nxp, nyp, nzp;
    float aa2[2];
    {
      const size_t p0 = cbase + (size_t)(row0 + r) * 3;
      const size_t p1 = cbase + (size_t)(row0 + 16 + r) * 3;
      const float x0 = pred[p0], y0 = pred[p0 + 1], z0 = pred[p0 + 2];
      const float x1 = pred[p1], y1 = pred[p1 + 1], z1 = pred[p1 + 2];
      aa2[0] = fmaf(x0, x0, fmaf(y0, y0, z0 * z0));
      aa2[1] = fmaf(x1, x1, fmaf(y1, y1, z1 * z1));
      v2f a0 = {-2.f * x0, -2.f * x1}; nxp = a0;
      v2f a1 = {-2.f * y0, -2.f * y1}; nyp = a1;
      v2f a2 = {-2.f * z0, -2.f * z1}; nzp = a2;
    }
    // coverage coeffs (1 partial row/thread), duplicated pairs for vertical pk
    v2f cnxp, cnyp, cnzp;
    float caa;
    {
      const size_t p = ((size_t)b * K_ + prow0 + r) * 3;
      const float x = partial[p], y = partial[p + 1], z = partial[p + 2];
      caa = fmaf(x, x, fmaf(y, y, z * z));
      v2f c0 = {-2.f * x, -2.f * x}; cnxp = c0;
      v2f c1 = {-2.f * y, -2.f * y}; cnyp = c1;
      v2f c2 = {-2.f * z, -2.f * z}; cnzp = c2;
    }
    float cm0 = FLT_MAX, cm1 = FLT_MAX;

    float t8a[8], t8b[8];
#pragma unroll
    for (int i = 0; i < 8; ++i) { t8a[i] = FLT_MAX; t8b[i] = FLT_MAX; }

    // prologue: stage tile0, prefetch tile1 pairs into regs
    v2f pa[2], pb[2], pc[2];
#pragma unroll
    for (int k = 0; k < 2; ++k) {
      const int P = t + k * 256;
      pa[k] = gsrc[3 * P]; pb[k] = gsrc[3 * P + 1]; pc[k] = gsrc[3 * P + 2];
    }
#pragma unroll
    for (int k = 0; k < 2; ++k)
      PAIR_WRITE(tile2, t + k * 256, 5, 31, R3_GSTR2, pa[k], pb[k], pc[k]);
#pragma unroll
    for (int k = 0; k < 2; ++k) {
      const int P = t + k * 256;
      pa[k] = gsrc[1536 + 3 * P]; pb[k] = gsrc[1536 + 3 * P + 1];
      pc[k] = gsrc[1536 + 3 * P + 2];
    }
    __syncthreads();

    // one candidate-pair: both rows (packed) + coverage (cand-packed)
#define R3_UNIT(P, d0, d1, ui)                                                 \
    {                                                                          \
      const int p_ = (P);                                                      \
      const int sv_ = (p_ >> 2) & 3;                                           \
      const int b2_ = gb2 + p_ * 4;                                            \
      const v2f xp = t2[b2_ + (0 ^ sv_)];                                      \
      const v2f yp = t2[b2_ + (1 ^ sv_)];                                      \
      const v2f zp = t2[b2_ + (2 ^ sv_)];                                      \
      const v2f wp = t2[b2_ + (3 ^ sv_)];                                      \
      v2f sl = pk_fma_bclo(nzp, zp, wp);                                       \
      sl = pk_fma_blo(nyp, yp, sl);                                            \
      sl = pk_fma_blo(nxp, xp, sl);                                            \
      v2f sh = pk_fma_bchi(nzp, zp, wp);                                       \
      sh = pk_fma_bhi(nyp, yp, sh);                                            \
      sh = pk_fma_bhi(nxp, xp, sh);                                            \
      d0[2 * (ui)] = sl.x; d1[2 * (ui)] = sl.y;                                \
      d0[2 * (ui) + 1] = sh.x; d1[2 * (ui) + 1] = sh.y;                        \
      v2f cs = pk_fma_n(cnzp, zp, wp);                                         \
      cs = pk_fma_n(cnyp, yp, cs);                                             \
      cs = pk_fma_n(cnxp, xp, cs);                                             \
      cm0 = fminf(cm0, cs.x); cm1 = fminf(cm1, cs.y);                          \
    }

#pragma unroll 1
    for (int T = 0; T < 4; ++T) {
      const v2f* t2 = tile2 + (T & 1) * R3_BUF2;
      for (int win = 0; win < 4; ++win) {  // 8 pairs = 16 cands per window
        float sA0[8], sA1[8], sB0[8], sB1[8];
#pragma unroll
        for (int u = 0; u < 4; ++u) R3_UNIT(win * 8 + u, sA0, sA1, u);
#pragma unroll
        for (int u = 0; u < 4; ++u) R3_UNIT(win * 8 + 4 + u, sB0, sB1, u);
        select8(t8a, sA0, sB0);
        select8(t8b, sA1, sB1);
      }
      if (T < 3) {  // stage tile T+1 from held regs, prefetch T+2
        v2f* nb = tile2 + ((T + 1) & 1) * R3_BUF2;
#pragma unroll
        for (int k = 0; k < 2; ++k)
          PAIR_WRITE(nb, t + k * 256, 5, 31, R3_GSTR2, pa[k], pb[k], pc[k]);
        if (T < 2) {
#pragma unroll
          for (int k = 0; k < 2; ++k) {
            const int P = t + k * 256;
            const int o = (T + 2) * 1536 + 3 * P;
            pa[k] = gsrc[o]; pb[k] = gsrc[o + 1]; pc[k] = gsrc[o + 2];
          }
        }
      }
      __syncthreads();
    }
#undef R3_UNIT

    // ---- epilogue: merge lists + coverage reduce (overlaid on buffers) ----
#pragma unroll
    for (int i = 0; i < 8; ++i) smem_f[(0 * 16 + r) * 144 + g * 9 + i] = t8a[i];
#pragma unroll
    for (int i = 0; i < 8; ++i) smem_f[(1 * 16 + r) * 144 + g * 9 + i] = t8b[i];
    if (g == 0) {
      smem_f[AA_OFF + r] = aa2[0];
      smem_f[AA_OFF + 16 + r] = aa2[1];
    }
    smem_f[COV_OFF + r * 17 + g] = fminf(cm0, cm1);
    __syncthreads();
    // L1: 256 pair-merges (8+8 -> full 16, in place), 1 per thread
    fullmerge8_inplace(&smem_f[(t >> 3) * 144 + (t & 7) * 18]);
    __syncthreads();
    if (t < 128) {  // L2: 128 keep-16 merges
      float* A = &smem_f[(t >> 2) * 144 + (t & 3) * 36];
      keep16_lds(A, A + 18);
    } else if (t < 192) {  // wave 2: coverage cross-group reduce
      const int lane = t - 128;
      float d = 0.f;
      if (lane < 16) {
        float mm = FLT_MAX;
#pragma unroll
        for (int k = 0; k < 16; ++k) mm = fminf(mm, smem_f[COV_OFF + lane * 17 + k]);
        d = sqrtf(fmaxf(mm + caa, 1e-12f));  // caa matches: r == lane here
      }
      d = wave_sum(d);
      if (t == 128) ws[WS_COV + rid] = d;
    }
    __syncthreads();
    if (t < 64) {  // L3: 64 keep-16 merges
      float* A = &smem_f[(t >> 1) * 144 + (t & 1) * 72];
      keep16_lds(A, A + 36);
    }
    __syncthreads();
    if (t < 64) {  // L4 + stats: 32 rows on wave 0
      float rep_acc = 0.f, var_acc = 0.f;
      if (t < 32) {
        const float* A = &smem_f[t * 144];
        const float* Bl = A + 72;
        float f[16];
#pragma unroll
        for (int i = 0; i < 16; ++i) f[i] = fminf(A[i], Bl[15 - i]);
        bitonic_merge16_asc(f);
        const float aar = smem_f[AA_OFF + t];
        float d16[16], sum = 0.f;
#pragma unroll
        for (int i = 0; i < 16; ++i) {
          d16[i] = sqrtf(fmaxf(f[i] + aar, 1e-12f));  // self -> 1e-6, rank 0
          sum += d16[i];
        }
        const float mean = sum * 0.0625f;
        float var = 0.f;
#pragma unroll
        for (int i = 0; i < 16; ++i) {
          float e = d16[i] - mean;
          var = fmaf(e, e, var);
        }
        var_acc = var * (1.f / 15.f);  // unbiased
#pragma unroll
        for (int i = 1; i <= 4; ++i) rep_acc += fmaxf(0.01f - d16[i], 0.f);
      }
      const float rs = wave_sum(rep_acc);
      const float vs = wave_sum(var_acc);
      if (t == 0) {
        ws[WS_REP + rid] = rs;
        ws[WS_SMO + rid] = vs;
      }
    }
  } else {
    // ======= chamfer: pred->gt / gt->pred, 8 rows as 4 packed row-pairs =======
    const int mid = blk - R3_NB;
    const int role = (mid < CD_NB) ? 0 : 1;
    const int rel = (role == 0) ? mid : mid - CD_NB;

    const int r = t & 7;         // row slot (8)
    const int g = t >> 3;        // group (32 groups x 32 cands = 16 pairs)
    const int gb2 = g * CD_GSTR2;

    const int b = rel >> 6;               // 64 blocks/batch
    const int row0 = (rel & 63) * 64;

    const float* colsrc = (role == 0) ? gt : pred;
    const float* rowsrc = (role == 1) ? gt : pred;
    const size_t cbase = (size_t)b * N_ * 3;
    const v2f* gsrc = reinterpret_cast<const v2f*>(colsrc + cbase);

    v2f nxp[4], nyp[4], nzp[4];
    float aa8[8];
#pragma unroll
    for (int rp = 0; rp < 4; ++rp) {
      const size_t p0 = ((size_t)b * N_ + row0 + (2 * rp) * 8 + r) * 3;
      const size_t p1 = ((size_t)b * N_ + row0 + (2 * rp + 1) * 8 + r) * 3;
      const float x0 = rowsrc[p0], y0 = rowsrc[p0 + 1], z0 = rowsrc[p0 + 2];
      const float x1 = rowsrc[p1], y1 = rowsrc[p1 + 1], z1 = rowsrc[p1 + 2];
      aa8[2 * rp] = fmaf(x0, x0, fmaf(y0, y0, z0 * z0));
      aa8[2 * rp + 1] = fmaf(x1, x1, fmaf(y1, y1, z1 * z1));
      v2f a0 = {-2.f * x0, -2.f * x1}; nxp[rp] = a0;
      v2f a1 = {-2.f * y0, -2.f * y1}; nyp[rp] = a1;
      v2f a2 = {-2.f * z0, -2.f * z1}; nzp[rp] = a2;
    }

    // chains: m[rp*4 + 0,1] = rows (2rp,2rp+1) over even cands; +2,3 odd cands
    float m[16];
#pragma unroll
    for (int i = 0; i < 16; ++i) m[i] = FLT_MAX;

    // prologue: stage tile0, prefetch tile1
    v2f pa[2], pb[2], pc[2];
#pragma unroll
    for (int k = 0; k < 2; ++k) {
      const int P = t + k * 256;
      pa[k] = gsrc[3 * P]; pb[k] = gsrc[3 * P + 1]; pc[k] = gsrc[3 * P + 2];
    }
#pragma unroll
    for (int k = 0; k < 2; ++k)
      PAIR_WRITE(tile2, t + k * 256, 4, 15, CD_GSTR2, pa[k], pb[k], pc[k]);
#pragma unroll
    for (int k = 0; k < 2; ++k) {
      const int P = t + k * 256;
      pa[k] = gsrc[1536 + 3 * P]; pb[k] = gsrc[1536 + 3 * P + 1];
      pc[k] = gsrc[1536 + 3 * P + 2];
    }
    __syncthreads();

#pragma unroll 1
    for (int T = 0; T < 4; ++T) {
      const v2f* t2 = tile2 + (T & 1) * CD_BUF2;

#pragma unroll 4
      for (int p = 0; p < 16; ++p) {  // 16 cand-pairs per tile per group
        const int sv_ = (p >> 2) & 3;
        const int b2_ = gb2 + p * 4;
        const v2f xp = t2[b2_ + (0 ^ sv_)];
        const v2f yp = t2[b2_ + (1 ^ sv_)];
        const v2f zp = t2[b2_ + (2 ^ sv_)];
        const v2f wp = t2[b2_ + (3 ^ sv_)];
#pragma unroll
        for (int rp = 0; rp < 4; ++rp) {
          v2f sl = pk_fma_bclo(nzp[rp], zp, wp);
          sl = pk_fma_blo(nyp[rp], yp, sl);
          sl = pk_fma_blo(nxp[rp], xp, sl);
          m[rp * 4 + 0] = fminf(m[rp * 4 + 0], sl.x);
          m[rp * 4 + 1] = fminf(m[rp * 4 + 1], sl.y);
          v2f sh = pk_fma_bchi(nzp[rp], zp, wp);
          sh = pk_fma_bhi(nyp[rp], yp, sh);
          sh = pk_fma_bhi(nxp[rp], xp, sh);
          m[rp * 4 + 2] = fminf(m[rp * 4 + 2], sh.x);
          m[rp * 4 + 3] = fminf(m[rp * 4 + 3], sh.y);
        }
      }

      if (T < 3) {
        v2f* nb = tile2 + ((T + 1) & 1) * CD_BUF2;
#pragma unroll
        for (int k = 0; k < 2; ++k)
          PAIR_WRITE(nb, t + k * 256, 4, 15, CD_GSTR2, pa[k], pb[k], pc[k]);
        if (T < 2) {
#pragma unroll
          for (int k = 0; k < 2; ++k) {
            const int P = t + k * 256;
            const int o = (T + 2) * 1536 + 3 * P;
            pa[k] = gsrc[o]; pb[k] = gsrc[o + 1]; pc[k] = gsrc[o + 2];
          }
        }
      }
      __syncthreads();
    }

#pragma unroll
    for (int q = 0; q < 8; ++q) {
      const int rp = q >> 1, e = q & 1;
      // +aa[q] constant per row: commutes with the cross-group min
      const float mm = fminf(m[rp * 4 + e], m[rp * 4 + 2 + e]) + aa8[q];
      smem_f[(q * 8 + r) * 33 + g] = mm;  // stride 33: conflict-light
    }
    __syncthreads();
    if (t < 64) {  // wave 0: one row per lane
      float mm = FLT_MAX;
#pragma unroll
      for (int k = 0; k < 32; ++k) mm = fminf(mm, smem_f[t * 33 + k]);
      float d = sqrtf(fmaxf(mm, 1e-12f));
      d = wave_sum(d);
      if (t == 0) {
        const int slot = (role == 0) ? WS_CD1 + rel : WS_CD2 + rel;
        ws[slot] = d;
      }
    }
  }
#undef PAIR_WRITE
}

__global__ void finalize(const float* __restrict__ ws, float* __restrict__ out) {
  __shared__ float sc[20];
  const int t = threadIdx.x;
  const int offs[5] = {WS_REP, WS_SMO, WS_CD1, WS_CD2, WS_COV};
  const int lens[5] = {512, 512, 256, 256, 512};
  float v[5];
#pragma unroll
  for (int s5 = 0; s5 < 5; ++s5) {
    float s = 0.f;
    for (int i = t; i < lens[s5]; i += TPB) s += ws[offs[s5] + i];
    v[s5] = wave_sum(s);
  }
  if ((t & 63) == 0) {
#pragma unroll
    for (int s5 = 0; s5 < 5; ++s5) sc[s5 * 4 + (t >> 6)] = v[s5];
  }
  __syncthreads();
  if (t == 0) {
    float S[5];
#pragma unroll
    for (int s5 = 0; s5 < 5; ++s5)
      S[s5] = sc[s5 * 4] + sc[s5 * 4 + 1] + sc[s5 * 4 + 2] + sc[s5 * 4 + 3];
    const float rep    = S[0] / (float)(B_ * N_ * 4);
    const float smooth = S[1] / (float)(B_ * N_);
    const float cd     = (S[2] + S[3]) / (float)(B_ * N_);
    const float cov    = S[4] / (float)(B_ * K_);
    const float total  = 1.0f * cd + 0.01f * rep + 0.005f * smooth + 0.1f * cov;
    out[0] = total;
    out[1] = cd;
    out[2] = rep;
    out[3] = smooth;
    out[4] = cov;
  }
}

extern "C" void kernel_launch(void* const* d_in, const int* in_sizes, int n_in,
                              void* d_out, int out_size, void* d_ws, size_t ws_size,
                              hipStream_t stream) {
  const float* pred    = (const float*)d_in[0];  // [4,4096,3]
  const float* gt      = (const float*)d_in[1];  // [4,4096,3]
  const float* partial = (const float*)d_in[2];  // [4,2048,3]
  float* out = (float*)d_out;                    // 5 scalars
  float* ws  = (float*)d_ws;                     // >= 2048 floats, all written each call

  fused_loss<<<GRID, TPB, 0, stream>>>(pred, gt, partial, ws);
  finalize<<<1, TPB, 0, stream>>>(ws, out);
}